// Round 15
// baseline (201.676 us; speedup 1.0000x reference)
//
#include <hip/hip_runtime.h>
#include <math.h>

#define T_TOK 4096
#define D_DIM 1024
#define H_DIM 2048
#define NE 8
#define EPSF 1e-8f
#define G1_GEMM 448   // 56 tiles * 8 n0  (BN=256)
#define G2_GEMM 224   // 56 tiles * 4 n0  (BN=256)
#define NTR128 1152   // 9 matrices * 128 tiles of 128x128

typedef __attribute__((ext_vector_type(8))) short bf16x8;
typedef __attribute__((ext_vector_type(4))) float f32x4;

__device__ __forceinline__ unsigned short f2bf(float f) {
  unsigned u = __float_as_uint(f);
  u += 0x7fffu + ((u >> 16) & 1u);
  return (unsigned short)(u >> 16);
}

__device__ __forceinline__ float bf2f(unsigned short u) {
  return __uint_as_float((unsigned)u << 16);
}

__device__ __forceinline__ void gload_lds16(const void* g, void* l) {
  __builtin_amdgcn_global_load_lds(
      (const __attribute__((address_space(1))) unsigned int*)g,
      (__attribute__((address_space(3))) unsigned int*)l, 16, 0, 0);
}

#define WAITV(n) asm volatile("s_waitcnt vmcnt(" #n ")" ::: "memory")
#define BARR()                                  \
  do {                                          \
    asm volatile("" ::: "memory");              \
    __builtin_amdgcn_s_barrier();               \
    asm volatile("" ::: "memory");              \
  } while (0)

// ---------------------------------------------------------------- 128x128 transpose tile
__device__ __forceinline__ void transpose_tile128(const float* __restrict__ src,
                                                  unsigned short* __restrict__ dst,
                                                  int R, int C, int r0, int c0, int tid,
                                                  float* tile) {
#pragma unroll
  for (int k = 0; k < 8; ++k) {
    int id = tid + k * 512;
    int row = id >> 5, c4 = (id & 31) * 4;
    float4 v = *(const float4*)(src + (size_t)(r0 + row) * C + c0 + c4);
    float* tr = tile + row * 129 + c4;
    tr[0] = v.x; tr[1] = v.y; tr[2] = v.z; tr[3] = v.w;
  }
  __syncthreads();
#pragma unroll
  for (int k = 0; k < 4; ++k) {
    int id = tid + k * 512;
    int oc = id >> 4;
    int rbase = (id & 15) * 8;
    uint4 wv;
    unsigned* wp = (unsigned*)&wv;
#pragma unroll
    for (int j = 0; j < 4; ++j) {
      unsigned lo = f2bf(tile[(rbase + 2 * j) * 129 + oc]);
      unsigned hi = f2bf(tile[(rbase + 2 * j + 1) * 129 + oc]);
      wp[j] = lo | (hi << 16);
    }
    *(uint4*)(dst + (size_t)(c0 + oc) * R + r0 + rbase) = wv;
  }
}

// ---------------------------------------------------------------- prep2: gate+cast | transW1
__global__ __launch_bounds__(512, 4) void prep2_kernel(
    const float* __restrict__ x, const float* __restrict__ gW, const float* __restrict__ gb,
    const float* __restrict__ gtemp, const float* __restrict__ W1, const float* __restrict__ sW1,
    unsigned short* __restrict__ W1t, unsigned short* __restrict__ sW1t,
    unsigned short* __restrict__ xb, float* __restrict__ scores, int* __restrict__ idx,
    unsigned* __restrict__ usage, unsigned* __restrict__ cnt, int* __restrict__ perm) {
  __shared__ char psm[67584];
  int b = blockIdx.x, tid = threadIdx.x;
  if (b >= 512) {
    int l = b - 512;
    int m = l >> 7, rem = l & 127;
    int c0 = (rem & 15) * 128, r0 = (rem >> 4) * 128;
    const float* src = (m < NE) ? W1 + (size_t)m * D_DIM * H_DIM : sW1;
    unsigned short* dst = (m < NE) ? W1t + (size_t)m * D_DIM * H_DIM : sW1t;
    transpose_tile128(src, dst, D_DIM, H_DIM, r0, c0, tid, (float*)psm);
    return;
  }
  float* gWl = (float*)psm;
  int* toks = (int*)(psm + 36864);
  int wave = tid >> 6, lane = tid & 63;
  int t0 = b * 8;
#pragma unroll
  for (int k = 0; k < 4; ++k) {
    int q = tid + k * 512;
    float4 f = ((const float4*)gW)[q];
    int d = q >> 1, eo = (q & 1) * 4;
    float* dstv = &gWl[d * 9 + eo];
    dstv[0] = f.x; dstv[1] = f.y; dstv[2] = f.z; dstv[3] = f.w;
  }
  __syncthreads();
  int t = t0 + wave;
  const float* xr = x + (size_t)t * D_DIM;
  unsigned short* xbr = xb + (size_t)t * D_DIM;
  float part[NE];
#pragma unroll
  for (int e = 0; e < NE; ++e) part[e] = 0.f;
#pragma unroll
  for (int i = 0; i < 16; ++i) {
    int d = lane + 64 * i;
    float xv = xr[d];
    xbr[d] = f2bf(xv);
    const float* g = &gWl[d * 9];
#pragma unroll
    for (int e = 0; e < NE; ++e) part[e] += xv * g[e];
  }
#pragma unroll
  for (int e = 0; e < NE; ++e) {
    float v = part[e];
    for (int off = 32; off; off >>= 1) v += __shfl_xor(v, off);
    part[e] = v;
  }
  float temp = gtemp[0];
  float mx = -1e30f;
#pragma unroll
  for (int e = 0; e < NE; ++e) { part[e] = (part[e] + gb[e]) / temp; mx = fmaxf(mx, part[e]); }
  float s = 0.f;
#pragma unroll
  for (int e = 0; e < NE; ++e) { part[e] = expf(part[e] - mx); s += part[e]; }
  float inv = 1.0f / s;
#pragma unroll
  for (int e = 0; e < NE; ++e) part[e] *= inv;
  if (lane == 0) {
    float4* sp = (float4*)(scores + (size_t)t * NE);
    sp[0] = make_float4(part[0], part[1], part[2], part[3]);
    sp[1] = make_float4(part[4], part[5], part[6], part[7]);
    int i0 = 0; float b0 = part[0];
#pragma unroll
    for (int e = 1; e < NE; ++e) if (part[e] > b0) { b0 = part[e]; i0 = e; }
    int i1 = -1; float b1 = -1e30f;
#pragma unroll
    for (int e = 0; e < NE; ++e) if (e != i0 && part[e] > b1) { b1 = part[e]; i1 = e; }
    idx[t * 2] = i0; idx[t * 2 + 1] = i1;
    toks[wave * 2] = i0; toks[wave * 2 + 1] = i1;
  }
  __syncthreads();
  if (tid < NE) {
    int c0 = 0, c1 = 0;
#pragma unroll
    for (int j = 0; j < 8; ++j) {
      if (toks[j * 2] == tid) ++c0;
      if (toks[j * 2 + 1] == tid) ++c1;
    }
    if (c0) atomicAdd(&usage[tid], (unsigned)c0);
    int tot = c0 + c1;
    if (tot) {
      unsigned bb = atomicAdd(&cnt[tid], (unsigned)tot);
      int p = 0;
#pragma unroll
      for (int j = 0; j < 8; ++j) {
        if (toks[j * 2] == tid) perm[(size_t)tid * T_TOK + bb + p++] = (t0 + j) * 2;
        if (toks[j * 2 + 1] == tid) perm[(size_t)tid * T_TOK + bb + p++] = (t0 + j) * 2 + 1;
      }
    }
  }
}

// ---------------------------------------------------------------- EM (512 threads) + KL loss
__device__ __forceinline__ void em_block512(const float* __restrict__ scores,
                                            const unsigned* __restrict__ usage,
                                            float* __restrict__ p_out, float* __restrict__ loss_out,
                                            int tid, char* smem) {
  float* p_sh = (float*)smem;
  float* cw = p_sh + 8;
  float* counts_sh = cw + 64;
  int wave = tid >> 6, lane = tid & 63;
  float s[8][NE];
#pragma unroll
  for (int rr = 0; rr < 8; ++rr) {
    int row = tid + rr * 512;
    const float4* sp = (const float4*)(scores + (size_t)row * NE);
    float4 a = sp[0], b = sp[1];
    s[rr][0] = a.x; s[rr][1] = a.y; s[rr][2] = a.z; s[rr][3] = a.w;
    s[rr][4] = b.x; s[rr][5] = b.y; s[rr][6] = b.z; s[rr][7] = b.w;
  }
  if (tid < NE) p_sh[tid] = 1.0f / NE;
  __syncthreads();
  for (int it = 0; it < 5; ++it) {
    float p[NE];
#pragma unroll
    for (int e = 0; e < NE; ++e) p[e] = p_sh[e];
    float c[NE];
#pragma unroll
    for (int e = 0; e < NE; ++e) c[e] = 0.f;
#pragma unroll
    for (int rr = 0; rr < 8; ++rr) {
      float denom = 0.f;
#pragma unroll
      for (int e = 0; e < NE; ++e) denom += s[rr][e] * p[e];
      float inv = 1.0f / (denom + EPSF);
#pragma unroll
      for (int e = 0; e < NE; ++e) c[e] += s[rr][e] * p[e] * inv;
    }
#pragma unroll
    for (int e = 0; e < NE; ++e) {
      float v = c[e];
      for (int off = 32; off; off >>= 1) v += __shfl_xor(v, off);
      c[e] = v;
    }
    if (lane == 0) {
#pragma unroll
      for (int e = 0; e < NE; ++e) cw[wave * 8 + e] = c[e];
    }
    __syncthreads();
    if (tid < NE) {
      float tot = 0.f;
#pragma unroll
      for (int w = 0; w < 8; ++w) tot += cw[w * 8 + tid];
      counts_sh[tid] = tot;
    }
    __syncthreads();
    if (tid < NE) {
      float total = 0.f;
#pragma unroll
      for (int e = 0; e < NE; ++e) total += counts_sh[e];
      p_sh[tid] = counts_sh[tid] / (total + EPSF);
    }
    __syncthreads();
  }
  if (tid < NE) p_out[tid] = p_sh[tid];
  if (tid == 0) {
    float actual[NE]; float norm = 0.f;
#pragma unroll
    for (int e = 0; e < NE; ++e) { actual[e] = (float)usage[e] / (float)T_TOK + EPSF; norm += actual[e]; }
    float u = 1.0f / NE;
    float kl = 0.f;
#pragma unroll
    for (int e = 0; e < NE; ++e) kl += u * (logf(u) - logf(actual[e] / norm));
    loss_out[0] = 0.1f * kl;
  }
}

// ---------------------------------------------------------------- 256x256 BK=64 merged-4-phase GEMM body
// (UNCHANGED from champion — gemm1's codegen must stay identical.)
template <int KDIM, int NDIM, bool RELU, bool MODE1, bool OBF16>
__device__ __forceinline__ void gemm_body(
    unsigned short* lds, int flat,
    const unsigned short* __restrict__ A, const unsigned short* __restrict__ WE,
    const unsigned short* __restrict__ WS, const float* __restrict__ biasE,
    const float* __restrict__ biasS, const int* __restrict__ perm,
    const unsigned* __restrict__ cnt, void* __restrict__ outp) {
  constexpr int BM = 256, BN = 256, BK = 64;
  constexpr int NT = NDIM / BN;
  constexpr int NKT = KDIM / BK;

  int tc[9];
#pragma unroll
  for (int i = 0; i < NE; ++i) tc[i] = ((int)cnt[i] + 255) >> 8;
  tc[8] = T_TOK / 256;
  int nt = 0;
#pragma unroll
  for (int i = 0; i < 9; ++i) nt += tc[i];
  int W = nt * NT;
  int xcd = flat & 7, pos = flat >> 3;
  int q = W >> 3, r = W & 7;
  int mycount = q + (xcd < r ? 1 : 0);
  if (pos >= mycount) return;
  int mystart = xcd * q + (xcd < r ? xcd : r);
  int w = mystart + pos;
  int ti = w / NT;
  int n0 = (w % NT) * BN;
  int e = 0, mt = ti;
  while (mt >= tc[e]) { mt -= tc[e]; ++e; }
  int m0 = mt * BM;
  int cnt_e = (e == NE) ? T_TOK : (int)cnt[e];

  const unsigned short* Bmat = (e == NE) ? WS : WE + (size_t)e * KDIM * NDIM;
  const float* bias = (e == NE) ? biasS : biasE + (size_t)e * NDIM;

  int tid = threadIdx.x, wave = tid >> 6, lane = tid & 63;
  int wm = wave >> 1, wn = wave & 1;
  int frow = lane & 15, fks = lane >> 4;

  int srow = wave * 8 + (lane >> 3);
  int sslot = lane & 7;
  const unsigned short* aptr[2][2];
  const unsigned short* bptr[2][2];
#pragma unroll
  for (int h = 0; h < 2; ++h)
#pragma unroll
    for (int j = 0; j < 2; ++j) {
      int rr = h * 128 + j * 64 + srow;
      int colsw = (sslot ^ (rr & 7)) << 3;
      int ar = m0 + rr;
      if (ar > cnt_e - 1) ar = cnt_e - 1;
      int gar;
      if (e == NE) gar = MODE1 ? ar : (2 * T_TOK + ar);
      else { int v = perm[(size_t)e * T_TOK + ar]; gar = MODE1 ? (v >> 1) : v; }
      aptr[h][j] = A + (size_t)gar * KDIM + colsw;
      bptr[h][j] = Bmat + (size_t)(n0 + rr) * KDIM + colsw;
    }

  auto stA = [&](int t, int h) {
    int dbe = (t & 1) * 16384;
    int k0 = t * BK;
    gload_lds16(aptr[h][0] + k0, &lds[dbe + h * 8192 + wave * 512]);
    gload_lds16(aptr[h][1] + k0, &lds[dbe + h * 8192 + wave * 512 + 4096]);
  };
  auto stB = [&](int t, int h) {
    int dbe = (t & 1) * 16384;
    int k0 = t * BK;
    gload_lds16(bptr[h][0] + k0, &lds[32768 + dbe + h * 8192 + wave * 512]);
    gload_lds16(bptr[h][1] + k0, &lds[32768 + dbe + h * 8192 + wave * 512 + 4096]);
  };

  auto rdA = [&](int dbe, int ks, int m) -> bf16x8 {
    int rr = wm * 64 + m * 16 + frow;
    int slot = (ks * 4 + fks) ^ (rr & 7);
    return *(const bf16x8*)&lds[dbe + rr * 64 + slot * 8];
  };
  auto rdB = [&](int dbe, int ks, int bh, int jj) -> bf16x8 {
    int rr = bh * 128 + jj * 32 + wn * 16 + frow;
    int slot = (ks * 4 + fks) ^ (rr & 7);
    return *(const bf16x8*)&lds[32768 + dbe + rr * 64 + slot * 8];
  };

  f32x4 acc[4][8];
#pragma unroll
  for (int m = 0; m < 4; ++m)
#pragma unroll
    for (int nn = 0; nn < 8; ++nn) acc[m][nn] = (f32x4){0.f, 0.f, 0.f, 0.f};

  stA(0, 0); stA(0, 1);
  stB(0, 0); stB(0, 1);
  stA(1, 0); stA(1, 1);
  WAITV(4);
  BARR();

  for (int t = 0; t < NKT; ++t) {
    const int dbe = (t & 1) * 16384;
    bf16x8 a0[4], a1[4], b0[4], b1[4];

#pragma unroll
    for (int m = 0; m < 4; ++m) a0[m] = rdA(dbe, 0, m);
#pragma unroll
    for (int m = 0; m < 4; ++m) a1[m] = rdA(dbe, 1, m);
#pragma unroll
    for (int jj = 0; jj < 4; ++jj) b0[jj] = rdB(dbe, 0, 0, jj);
#pragma unroll
    for (int jj = 0; jj < 4; ++jj) b1[jj] = rdB(dbe, 1, 0, jj);
    if (t + 1 < NKT) { stB(t + 1, 0); stB(t + 1, 1); }
    BARR();
    __builtin_amdgcn_s_setprio(1);
#pragma unroll
    for (int m = 0; m < 4; ++m)
#pragma unroll
      for (int jj = 0; jj < 4; ++jj)
        acc[m][jj] = __builtin_amdgcn_mfma_f32_16x16x32_bf16(a0[m], b0[jj], acc[m][jj], 0, 0, 0);
#pragma unroll
    for (int m = 0; m < 4; ++m)
#pragma unroll
      for (int jj = 0; jj < 4; ++jj)
        acc[m][jj] = __builtin_amdgcn_mfma_f32_16x16x32_bf16(a1[m], b1[jj], acc[m][jj], 0, 0, 0);
    __builtin_amdgcn_s_setprio(0);
    BARR();

#pragma unroll
    for (int jj = 0; jj < 4; ++jj) b0[jj] = rdB(dbe, 0, 1, jj);
#pragma unroll
    for (int jj = 0; jj < 4; ++jj) b1[jj] = rdB(dbe, 1, 1, jj);
    if (t + 2 < NKT) { stA(t + 2, 0); stA(t + 2, 1); }
    BARR();
    __builtin_amdgcn_s_setprio(1);
#pragma unroll
    for (int m = 0; m < 4; ++m)
#pragma unroll
      for (int jj = 0; jj < 4; ++jj)
        acc[m][4 + jj] = __builtin_amdgcn_mfma_f32_16x16x32_bf16(a0[m], b0[jj], acc[m][4 + jj], 0, 0, 0);
#pragma unroll
    for (int m = 0; m < 4; ++m)
#pragma unroll
      for (int jj = 0; jj < 4; ++jj)
        acc[m][4 + jj] = __builtin_amdgcn_mfma_f32_16x16x32_bf16(a1[m], b1[jj], acc[m][4 + jj], 0, 0, 0);
    __builtin_amdgcn_s_setprio(0);
    if (t + 2 < NKT) { WAITV(4); }
    else if (t + 1 < NKT) { WAITV(0); }
    BARR();
  }

#pragma unroll
  for (int m = 0; m < 4; ++m) {
#pragma unroll
    for (int qq = 0; qq < 4; ++qq) {
      int rt = wm * 64 + m * 16 + (lane >> 4) * 4 + qq;
      if (m0 + rt >= cnt_e) continue;
      int rr;
      if (e == NE) rr = 2 * T_TOK + m0 + rt;
      else rr = perm[(size_t)e * T_TOK + m0 + rt];
#pragma unroll
      for (int nn = 0; nn < 8; ++nn) {
        int col = n0 + (nn >> 2) * 128 + (nn & 3) * 32 + wn * 16 + (lane & 15);
        float val = acc[m][nn][qq] + bias[col];
        if (RELU) val = fmaxf(val, 0.f);
        if (MODE1 || OBF16)
          ((unsigned short*)outp)[(size_t)rr * NDIM + col] = f2bf(val);
        else
          ((float*)outp)[(size_t)rr * NDIM + col] = val;
      }
    }
  }
}

// ---------------------------------------------------------------- gemm2 split-K body (SEPARATE copy,
// compile-time KOFF; never instantiated by gemm1 -> gemm1 codegen untouched).
template <int KOFF, bool BIAS>
__device__ __forceinline__ void gemm_body_g2(
    unsigned short* lds, int flat,
    const unsigned short* __restrict__ A, const unsigned short* __restrict__ WE,
    const unsigned short* __restrict__ WS, const float* __restrict__ biasE,
    const float* __restrict__ biasS, const int* __restrict__ perm,
    const unsigned* __restrict__ cnt, unsigned short* __restrict__ outp) {
  constexpr int STR = H_DIM, NDIM = D_DIM, BM = 256, BN = 256, BK = 64;
  constexpr int NT = NDIM / BN;   // 4
  constexpr int NKT = 1024 / BK;  // 16

  int tc[9];
#pragma unroll
  for (int i = 0; i < NE; ++i) tc[i] = ((int)cnt[i] + 255) >> 8;
  tc[8] = T_TOK / 256;
  int nt = 0;
#pragma unroll
  for (int i = 0; i < 9; ++i) nt += tc[i];
  int W = nt * NT;
  int xcd = flat & 7, pos = flat >> 3;
  int q = W >> 3, r = W & 7;
  int mycount = q + (xcd < r ? 1 : 0);
  if (pos >= mycount) return;
  int mystart = xcd * q + (xcd < r ? xcd : r);
  int w = mystart + pos;
  int ti = w / NT;
  int n0 = (w % NT) * BN;
  int e = 0, mt = ti;
  while (mt >= tc[e]) { mt -= tc[e]; ++e; }
  int m0 = mt * BM;
  int cnt_e = (e == NE) ? T_TOK : (int)cnt[e];

  const unsigned short* Bmat = (e == NE) ? WS : WE + (size_t)e * STR * NDIM;
  const float* bias = (e == NE) ? biasS : biasE + (size_t)e * NDIM;

  int tid = threadIdx.x, wave = tid >> 6, lane = tid & 63;
  int wm = wave >> 1, wn = wave & 1;
  int frow = lane & 15, fks = lane >> 4;

  int srow = wave * 8 + (lane >> 3);
  int sslot = lane & 7;
  const unsigned short* aptr[2][2];
  const unsigned short* bptr[2][2];
#pragma unroll
  for (int h = 0; h < 2; ++h)
#pragma unroll
    for (int j = 0; j < 2; ++j) {
      int rr = h * 128 + j * 64 + srow;
      int colsw = (sslot ^ (rr & 7)) << 3;
      int ar = m0 + rr;
      if (ar > cnt_e - 1) ar = cnt_e - 1;
      int gar = (e == NE) ? (2 * T_TOK + ar) : perm[(size_t)e * T_TOK + ar];
      aptr[h][j] = A + (size_t)gar * STR + KOFF + colsw;
      bptr[h][j] = Bmat + (size_t)(n0 + rr) * STR + KOFF + colsw;
    }

  auto stA = [&](int t, int h) {
    int dbe = (t & 1) * 16384;
    int k0 = t * BK;
    gload_lds16(aptr[h][0] + k0, &lds[dbe + h * 8192 + wave * 512]);
    gload_lds16(aptr[h][1] + k0, &lds[dbe + h * 8192 + wave * 512 + 4096]);
  };
  auto stB = [&](int t, int h) {
    int dbe = (t & 1) * 16384;
    int k0 = t * BK;
    gload_lds16(bptr[h][0] + k0, &lds[32768 + dbe + h * 8192 + wave * 512]);
    gload_lds16(bptr[h][1] + k0, &lds[32768 + dbe + h * 8192 + wave * 512 + 4096]);
  };

  auto rdA = [&](int dbe, int ks, int m) -> bf16x8 {
    int rr = wm * 64 + m * 16 + frow;
    int slot = (ks * 4 + fks) ^ (rr & 7);
    return *(const bf16x8*)&lds[dbe + rr * 64 + slot * 8];
  };
  auto rdB = [&](int dbe, int ks, int bh, int jj) -> bf16x8 {
    int rr = bh * 128 + jj * 32 + wn * 16 + frow;
    int slot = (ks * 4 + fks) ^ (rr & 7);
    return *(const bf16x8*)&lds[32768 + dbe + rr * 64 + slot * 8];
  };

  f32x4 acc[4][8];
#pragma unroll
  for (int m = 0; m < 4; ++m)
#pragma unroll
    for (int nn = 0; nn < 8; ++nn) acc[m][nn] = (f32x4){0.f, 0.f, 0.f, 0.f};

  stA(0, 0); stA(0, 1);
  stB(0, 0); stB(0, 1);
  stA(1, 0); stA(1, 1);
  WAITV(4);
  BARR();

  for (int t = 0; t < NKT; ++t) {
    const int dbe = (t & 1) * 16384;
    bf16x8 a0[4], a1[4], b0[4], b1[4];

#pragma unroll
    for (int m = 0; m < 4; ++m) a0[m] = rdA(dbe, 0, m);
#pragma unroll
    for (int m = 0; m < 4; ++m) a1[m] = rdA(dbe, 1, m);
#pragma unroll
    for (int jj = 0; jj < 4; ++jj) b0[jj] = rdB(dbe, 0, 0, jj);
#pragma unroll
    for (int jj = 0; jj < 4; ++jj) b1[jj] = rdB(dbe, 1, 0, jj);
    if (t + 1 < NKT) { stB(t + 1, 0); stB(t + 1, 1); }
    BARR();
    __builtin_amdgcn_s_setprio(1);
#pragma unroll
    for (int m = 0; m < 4; ++m)
#pragma unroll
      for (int jj = 0; jj < 4; ++jj)
        acc[m][jj] = __builtin_amdgcn_mfma_f32_16x16x32_bf16(a0[m], b0[jj], acc[m][jj], 0, 0, 0);
#pragma unroll
    for (int m = 0; m < 4; ++m)
#pragma unroll
      for (int jj = 0; jj < 4; ++jj)
        acc[m][jj] = __builtin_amdgcn_mfma_f32_16x16x32_bf16(a1[m], b1[jj], acc[m][jj], 0, 0, 0);
    __builtin_amdgcn_s_setprio(0);
    BARR();

#pragma unroll
    for (int jj = 0; jj < 4; ++jj) b0[jj] = rdB(dbe, 0, 1, jj);
#pragma unroll
    for (int jj = 0; jj < 4; ++jj) b1[jj] = rdB(dbe, 1, 1, jj);
    if (t + 2 < NKT) { stA(t + 2, 0); stA(t + 2, 1); }
    BARR();
    __builtin_amdgcn_s_setprio(1);
#pragma unroll
    for (int m = 0; m < 4; ++m)
#pragma unroll
      for (int jj = 0; jj < 4; ++jj)
        acc[m][4 + jj] = __builtin_amdgcn_mfma_f32_16x16x32_bf16(a0[m], b0[jj], acc[m][4 + jj], 0, 0, 0);
#pragma unroll
    for (int m = 0; m < 4; ++m)
#pragma unroll
      for (int jj = 0; jj < 4; ++jj)
        acc[m][4 + jj] = __builtin_amdgcn_mfma_f32_16x16x32_bf16(a1[m], b1[jj], acc[m][4 + jj], 0, 0, 0);
    __builtin_amdgcn_s_setprio(0);
    if (t + 2 < NKT) { WAITV(4); }
    else if (t + 1 < NKT) { WAITV(0); }
    BARR();
  }

#pragma unroll
  for (int m = 0; m < 4; ++m) {
#pragma unroll
    for (int qq = 0; qq < 4; ++qq) {
      int rt = wm * 64 + m * 16 + (lane >> 4) * 4 + qq;
      if (m0 + rt >= cnt_e) continue;
      int rr;
      if (e == NE) rr = 2 * T_TOK + m0 + rt;
      else rr = perm[(size_t)e * T_TOK + m0 + rt];
#pragma unroll
      for (int nn = 0; nn < 8; ++nn) {
        int col = n0 + (nn >> 2) * 128 + (nn & 3) * 32 + wn * 16 + (lane & 15);
        float val = acc[m][nn][qq] + (BIAS ? bias[col] : 0.f);
        outp[(size_t)rr * NDIM + col] = f2bf(val);
      }
    }
  }
}

// ---------------------------------------------------------------- gemm1: GEMM | transpose W2 | em
__global__ __launch_bounds__(512, 2) void gemm1_kernel(
    const unsigned short* __restrict__ xb, const unsigned short* __restrict__ W1t,
    const unsigned short* __restrict__ sW1t, const float* __restrict__ b1,
    const float* __restrict__ sb1, const int* __restrict__ perm, const unsigned* __restrict__ cnt,
    unsigned short* __restrict__ Hbuf,
    const float* __restrict__ W2, const float* __restrict__ sW2,
    unsigned short* __restrict__ W2t, unsigned short* __restrict__ sW2t,
    const float* __restrict__ scores, const unsigned* __restrict__ usage,
    float* __restrict__ pbuf, float* __restrict__ loss_out) {
  __shared__ char smem[131072];
  int flat = blockIdx.x;
  if (flat < G1_GEMM) {
    gemm_body<D_DIM, H_DIM, true, true, false>((unsigned short*)smem, flat, xb, W1t, sW1t, b1,
                                               sb1, perm, cnt, (void*)Hbuf);
    return;
  }
  int l = flat - G1_GEMM;
  if (l < NTR128) {
    int m = l >> 7, rem = l & 127;
    int c0 = (rem & 7) * 128, r0 = (rem >> 3) * 128;
    const float* src = (m < NE) ? W2 + (size_t)m * H_DIM * D_DIM : sW2;
    unsigned short* dst = (m < NE) ? W2t + (size_t)m * H_DIM * D_DIM : sW2t;
    transpose_tile128(src, dst, H_DIM, D_DIM, r0, c0, threadIdx.x, (float*)smem);
    return;
  }
  em_block512(scores, usage, pbuf, loss_out, threadIdx.x, smem);
}

// ---------------------------------------------------------------- gemm2: split-K (y = K-half)
__global__ __launch_bounds__(512, 2) void gemm2_kernel(
    const unsigned short* __restrict__ Hbuf, const unsigned short* __restrict__ W2t,
    const unsigned short* __restrict__ sW2t, const float* __restrict__ b2,
    const float* __restrict__ sb2, const int* __restrict__ perm,
    const unsigned* __restrict__ cnt, unsigned short* __restrict__ eA,
    unsigned short* __restrict__ eB) {
  __shared__ char smem[131072];
  if (blockIdx.y == 0)
    gemm_body_g2<0, true>((unsigned short*)smem, blockIdx.x, Hbuf, W2t, sW2t, b2, sb2, perm, cnt,
                          eA);
  else
    gemm_body_g2<1024, false>((unsigned short*)smem, blockIdx.x, Hbuf, W2t, sW2t, b2, sb2, perm,
                              cnt, eB);
}

// ---------------------------------------------------------------- combine (bf16 eA+eB)
__global__ void combine_kernel(const unsigned short* __restrict__ eA,
                               const unsigned short* __restrict__ eB,
                               const float* __restrict__ scores,
                               const float* __restrict__ p, const int* __restrict__ idx,
                               float* __restrict__ out) {
  int gid = blockIdx.x * blockDim.x + threadIdx.x;
  int t = gid >> 8;
  int d4 = gid & 255;
  int e0 = idx[t * 2], e1 = idx[t * 2 + 1];
  float w0 = scores[(size_t)t * NE + e0] * p[e0];
  float w1 = scores[(size_t)t * NE + e1] * p[e1];
  size_t r0 = (size_t)(t * 2) * 256 + d4;
  size_t r1 = (size_t)(t * 2 + 1) * 256 + d4;
  size_t rs = (size_t)(2 * T_TOK + t) * 256 + d4;
  const ushort4* A4 = (const ushort4*)eA;
  const ushort4* B4 = (const ushort4*)eB;
  ushort4 a0 = A4[r0], c0 = B4[r0];
  ushort4 a1 = A4[r1], c1 = B4[r1];
  ushort4 as = A4[rs], cs = B4[rs];
  float4 o;
  o.x = w0 * (bf2f(a0.x) + bf2f(c0.x)) + w1 * (bf2f(a1.x) + bf2f(c1.x)) + 0.1f * (bf2f(as.x) + bf2f(cs.x));
  o.y = w0 * (bf2f(a0.y) + bf2f(c0.y)) + w1 * (bf2f(a1.y) + bf2f(c1.y)) + 0.1f * (bf2f(as.y) + bf2f(cs.y));
  o.z = w0 * (bf2f(a0.z) + bf2f(c0.z)) + w1 * (bf2f(a1.z) + bf2f(c1.z)) + 0.1f * (bf2f(as.z) + bf2f(cs.z));
  o.w = w0 * (bf2f(a0.w) + bf2f(c0.w)) + w1 * (bf2f(a1.w) + bf2f(c1.w)) + 0.1f * (bf2f(as.w) + bf2f(cs.w));
  ((float4*)out)[gid] = o;
}

// ---------------------------------------------------------------- launch
extern "C" void kernel_launch(void* const* d_in, const int* in_sizes, int n_in,
                              void* d_out, int out_size, void* d_ws, size_t ws_size,
                              hipStream_t stream) {
  const float* x     = (const float*)d_in[0];
  const float* gW    = (const float*)d_in[1];
  const float* gb    = (const float*)d_in[2];
  const float* gtemp = (const float*)d_in[3];
  const float* W1    = (const float*)d_in[4];
  const float* b1    = (const float*)d_in[5];
  const float* W2    = (const float*)d_in[6];
  const float* b2    = (const float*)d_in[7];
  const float* sW1   = (const float*)d_in[8];
  const float* sb1   = (const float*)d_in[9];
  const float* sW2   = (const float*)d_in[10];
  const float* sb2   = (const float*)d_in[11];
  float* out = (float*)d_out;

  char* ws = (char*)d_ws;
  size_t off = 0;
  auto take = [&](size_t b) { char* ptr = ws + off; off += (b + 255) & ~(size_t)255; return ptr; };
  unsigned short* xb   = (unsigned short*)take((size_t)T_TOK * D_DIM * 2);
  unsigned short* W1t  = (unsigned short*)take((size_t)NE * H_DIM * D_DIM * 2);
  unsigned short* sW1t = (unsigned short*)take((size_t)H_DIM * D_DIM * 2);
  unsigned short* W2t  = (unsigned short*)take((size_t)NE * D_DIM * H_DIM * 2);
  unsigned short* sW2t = (unsigned short*)take((size_t)D_DIM * H_DIM * 2);
  unsigned short* Hbuf = (unsigned short*)take((size_t)3 * T_TOK * H_DIM * 2);
  unsigned short* eA   = (unsigned short*)take((size_t)3 * T_TOK * D_DIM * 2);
  unsigned short* eB   = (unsigned short*)take((size_t)3 * T_TOK * D_DIM * 2);
  float* scores        = (float*)take((size_t)T_TOK * NE * 4);
  int* idx             = (int*)take((size_t)T_TOK * 2 * 4);
  int* perm            = (int*)take((size_t)NE * T_TOK * 4);
  unsigned* cnt        = (unsigned*)take(256);
  unsigned* usage      = (unsigned*)take(256);
  float* pbuf          = (float*)take(256);
  (void)n_in; (void)in_sizes; (void)out_size; (void)ws_size;

  hipMemsetAsync(cnt, 0, 512, stream);  // cnt + usage (adjacent 256B blocks)
  prep2_kernel<<<512 + NTR128, 512, 0, stream>>>(x, gW, gb, gtemp, W1, sW1, W1t, sW1t, xb,
                                                 scores, idx, usage, cnt, perm);
  gemm1_kernel<<<G1_GEMM + NTR128 + 1, 512, 0, stream>>>(
      xb, W1t, sW1t, b1, sb1, perm, cnt, Hbuf, W2, sW2, W2t, sW2t, scores, usage, pbuf,
      out + (size_t)T_TOK * D_DIM);
  gemm2_kernel<<<dim3(G2_GEMM, 2), 512, 0, stream>>>(Hbuf, W2t, sW2t, b2, sb2, perm, cnt, eA, eB);
  combine_kernel<<<(T_TOK * D_DIM / 4) / 256, 256, 0, stream>>>(eA, eB, scores, pbuf, idx, out);
}

// Round 16
// 191.861 us; speedup vs baseline: 1.0512x; 1.0512x over previous
//
#include <hip/hip_runtime.h>
#include <math.h>

#define T_TOK 4096
#define D_DIM 1024
#define H_DIM 2048
#define NE 8
#define EPSF 1e-8f
#define G1_GEMM 448   // 56 tiles * 8 n0  (BN=256)
#define G2_GEMM 224   // 56 tiles * 4 n0  (BN=256)
#define NTR128 1152   // 9 matrices * 128 tiles of 128x128

typedef __attribute__((ext_vector_type(8))) short bf16x8;
typedef __attribute__((ext_vector_type(4))) float f32x4;

__device__ __forceinline__ unsigned short f2bf(float f) {
  unsigned u = __float_as_uint(f);
  u += 0x7fffu + ((u >> 16) & 1u);
  return (unsigned short)(u >> 16);
}

__device__ __forceinline__ float bf2f(unsigned short u) {
  return __uint_as_float((unsigned)u << 16);
}

__device__ __forceinline__ void gload_lds16(const void* g, void* l) {
  __builtin_amdgcn_global_load_lds(
      (const __attribute__((address_space(1))) unsigned int*)g,
      (__attribute__((address_space(3))) unsigned int*)l, 16, 0, 0);
}

#define WAITV(n) asm volatile("s_waitcnt vmcnt(" #n ")" ::: "memory")
#define BARR()                                  \
  do {                                          \
    asm volatile("" ::: "memory");              \
    __builtin_amdgcn_s_barrier();               \
    asm volatile("" ::: "memory");              \
  } while (0)

// ---------------------------------------------------------------- 128x128 transpose tile
__device__ __forceinline__ void transpose_tile128(const float* __restrict__ src,
                                                  unsigned short* __restrict__ dst,
                                                  int R, int C, int r0, int c0, int tid,
                                                  float* tile) {
#pragma unroll
  for (int k = 0; k < 8; ++k) {
    int id = tid + k * 512;
    int row = id >> 5, c4 = (id & 31) * 4;
    float4 v = *(const float4*)(src + (size_t)(r0 + row) * C + c0 + c4);
    float* tr = tile + row * 129 + c4;
    tr[0] = v.x; tr[1] = v.y; tr[2] = v.z; tr[3] = v.w;
  }
  __syncthreads();
#pragma unroll
  for (int k = 0; k < 4; ++k) {
    int id = tid + k * 512;
    int oc = id >> 4;
    int rbase = (id & 15) * 8;
    uint4 wv;
    unsigned* wp = (unsigned*)&wv;
#pragma unroll
    for (int j = 0; j < 4; ++j) {
      unsigned lo = f2bf(tile[(rbase + 2 * j) * 129 + oc]);
      unsigned hi = f2bf(tile[(rbase + 2 * j + 1) * 129 + oc]);
      wp[j] = lo | (hi << 16);
    }
    *(uint4*)(dst + (size_t)(c0 + oc) * R + r0 + rbase) = wv;
  }
}

// ---------------------------------------------------------------- prep2: gate+cast | transW1
__global__ __launch_bounds__(512, 4) void prep2_kernel(
    const float* __restrict__ x, const float* __restrict__ gW, const float* __restrict__ gb,
    const float* __restrict__ gtemp, const float* __restrict__ W1, const float* __restrict__ sW1,
    unsigned short* __restrict__ W1t, unsigned short* __restrict__ sW1t,
    unsigned short* __restrict__ xb, float* __restrict__ scores, int* __restrict__ idx,
    unsigned* __restrict__ usage, unsigned* __restrict__ cnt, int* __restrict__ perm) {
  __shared__ char psm[67584];
  int b = blockIdx.x, tid = threadIdx.x;
  if (b >= 512) {
    int l = b - 512;
    int m = l >> 7, rem = l & 127;
    int c0 = (rem & 15) * 128, r0 = (rem >> 4) * 128;
    const float* src = (m < NE) ? W1 + (size_t)m * D_DIM * H_DIM : sW1;
    unsigned short* dst = (m < NE) ? W1t + (size_t)m * D_DIM * H_DIM : sW1t;
    transpose_tile128(src, dst, D_DIM, H_DIM, r0, c0, tid, (float*)psm);
    return;
  }
  float* gWl = (float*)psm;
  int* toks = (int*)(psm + 36864);
  int wave = tid >> 6, lane = tid & 63;
  int t0 = b * 8;
#pragma unroll
  for (int k = 0; k < 4; ++k) {
    int q = tid + k * 512;
    float4 f = ((const float4*)gW)[q];
    int d = q >> 1, eo = (q & 1) * 4;
    float* dstv = &gWl[d * 9 + eo];
    dstv[0] = f.x; dstv[1] = f.y; dstv[2] = f.z; dstv[3] = f.w;
  }
  __syncthreads();
  int t = t0 + wave;
  const float* xr = x + (size_t)t * D_DIM;
  unsigned short* xbr = xb + (size_t)t * D_DIM;
  float part[NE];
#pragma unroll
  for (int e = 0; e < NE; ++e) part[e] = 0.f;
#pragma unroll
  for (int i = 0; i < 16; ++i) {
    int d = lane + 64 * i;
    float xv = xr[d];
    xbr[d] = f2bf(xv);
    const float* g = &gWl[d * 9];
#pragma unroll
    for (int e = 0; e < NE; ++e) part[e] += xv * g[e];
  }
#pragma unroll
  for (int e = 0; e < NE; ++e) {
    float v = part[e];
    for (int off = 32; off; off >>= 1) v += __shfl_xor(v, off);
    part[e] = v;
  }
  float temp = gtemp[0];
  float mx = -1e30f;
#pragma unroll
  for (int e = 0; e < NE; ++e) { part[e] = (part[e] + gb[e]) / temp; mx = fmaxf(mx, part[e]); }
  float s = 0.f;
#pragma unroll
  for (int e = 0; e < NE; ++e) { part[e] = expf(part[e] - mx); s += part[e]; }
  float inv = 1.0f / s;
#pragma unroll
  for (int e = 0; e < NE; ++e) part[e] *= inv;
  if (lane == 0) {
    float4* sp = (float4*)(scores + (size_t)t * NE);
    sp[0] = make_float4(part[0], part[1], part[2], part[3]);
    sp[1] = make_float4(part[4], part[5], part[6], part[7]);
    int i0 = 0; float b0 = part[0];
#pragma unroll
    for (int e = 1; e < NE; ++e) if (part[e] > b0) { b0 = part[e]; i0 = e; }
    int i1 = -1; float b1 = -1e30f;
#pragma unroll
    for (int e = 0; e < NE; ++e) if (e != i0 && part[e] > b1) { b1 = part[e]; i1 = e; }
    idx[t * 2] = i0; idx[t * 2 + 1] = i1;
    toks[wave * 2] = i0; toks[wave * 2 + 1] = i1;
  }
  __syncthreads();
  if (tid < NE) {
    int c0 = 0, c1 = 0;
#pragma unroll
    for (int j = 0; j < 8; ++j) {
      if (toks[j * 2] == tid) ++c0;
      if (toks[j * 2 + 1] == tid) ++c1;
    }
    if (c0) atomicAdd(&usage[tid], (unsigned)c0);
    int tot = c0 + c1;
    if (tot) {
      unsigned bb = atomicAdd(&cnt[tid], (unsigned)tot);
      int p = 0;
#pragma unroll
      for (int j = 0; j < 8; ++j) {
        if (toks[j * 2] == tid) perm[(size_t)tid * T_TOK + bb + p++] = (t0 + j) * 2;
        if (toks[j * 2 + 1] == tid) perm[(size_t)tid * T_TOK + bb + p++] = (t0 + j) * 2 + 1;
      }
    }
  }
}

// ---------------------------------------------------------------- EM (512 threads) + KL loss
__device__ __forceinline__ void em_block512(const float* __restrict__ scores,
                                            const unsigned* __restrict__ usage,
                                            float* __restrict__ p_out, float* __restrict__ loss_out,
                                            int tid, char* smem) {
  float* p_sh = (float*)smem;
  float* cw = p_sh + 8;
  float* counts_sh = cw + 64;
  int wave = tid >> 6, lane = tid & 63;
  float s[8][NE];
#pragma unroll
  for (int rr = 0; rr < 8; ++rr) {
    int row = tid + rr * 512;
    const float4* sp = (const float4*)(scores + (size_t)row * NE);
    float4 a = sp[0], b = sp[1];
    s[rr][0] = a.x; s[rr][1] = a.y; s[rr][2] = a.z; s[rr][3] = a.w;
    s[rr][4] = b.x; s[rr][5] = b.y; s[rr][6] = b.z; s[rr][7] = b.w;
  }
  if (tid < NE) p_sh[tid] = 1.0f / NE;
  __syncthreads();
  for (int it = 0; it < 5; ++it) {
    float p[NE];
#pragma unroll
    for (int e = 0; e < NE; ++e) p[e] = p_sh[e];
    float c[NE];
#pragma unroll
    for (int e = 0; e < NE; ++e) c[e] = 0.f;
#pragma unroll
    for (int rr = 0; rr < 8; ++rr) {
      float denom = 0.f;
#pragma unroll
      for (int e = 0; e < NE; ++e) denom += s[rr][e] * p[e];
      float inv = 1.0f / (denom + EPSF);
#pragma unroll
      for (int e = 0; e < NE; ++e) c[e] += s[rr][e] * p[e] * inv;
    }
#pragma unroll
    for (int e = 0; e < NE; ++e) {
      float v = c[e];
      for (int off = 32; off; off >>= 1) v += __shfl_xor(v, off);
      c[e] = v;
    }
    if (lane == 0) {
#pragma unroll
      for (int e = 0; e < NE; ++e) cw[wave * 8 + e] = c[e];
    }
    __syncthreads();
    if (tid < NE) {
      float tot = 0.f;
#pragma unroll
      for (int w = 0; w < 8; ++w) tot += cw[w * 8 + tid];
      counts_sh[tid] = tot;
    }
    __syncthreads();
    if (tid < NE) {
      float total = 0.f;
#pragma unroll
      for (int e = 0; e < NE; ++e) total += counts_sh[e];
      p_sh[tid] = counts_sh[tid] / (total + EPSF);
    }
    __syncthreads();
  }
  if (tid < NE) p_out[tid] = p_sh[tid];
  if (tid == 0) {
    float actual[NE]; float norm = 0.f;
#pragma unroll
    for (int e = 0; e < NE; ++e) { actual[e] = (float)usage[e] / (float)T_TOK + EPSF; norm += actual[e]; }
    float u = 1.0f / NE;
    float kl = 0.f;
#pragma unroll
    for (int e = 0; e < NE; ++e) kl += u * (logf(u) - logf(actual[e] / norm));
    loss_out[0] = 0.1f * kl;
  }
}

// ---------------------------------------------------------------- 256x256 BK=64 merged-4-phase GEMM body
// OBF16: write bf16 output without relu (gemm2 path).
template <int KDIM, int NDIM, bool RELU, bool MODE1, bool OBF16>
__device__ __forceinline__ void gemm_body(
    unsigned short* lds, int flat,
    const unsigned short* __restrict__ A, const unsigned short* __restrict__ WE,
    const unsigned short* __restrict__ WS, const float* __restrict__ biasE,
    const float* __restrict__ biasS, const int* __restrict__ perm,
    const unsigned* __restrict__ cnt, void* __restrict__ outp) {
  constexpr int BM = 256, BN = 256, BK = 64;
  constexpr int NT = NDIM / BN;
  constexpr int NKT = KDIM / BK;

  int tc[9];
#pragma unroll
  for (int i = 0; i < NE; ++i) tc[i] = ((int)cnt[i] + 255) >> 8;
  tc[8] = T_TOK / 256;
  int nt = 0;
#pragma unroll
  for (int i = 0; i < 9; ++i) nt += tc[i];
  int W = nt * NT;
  int xcd = flat & 7, pos = flat >> 3;
  int q = W >> 3, r = W & 7;
  int mycount = q + (xcd < r ? 1 : 0);
  if (pos >= mycount) return;
  int mystart = xcd * q + (xcd < r ? xcd : r);
  int w = mystart + pos;
  int ti = w / NT;
  int n0 = (w % NT) * BN;
  int e = 0, mt = ti;
  while (mt >= tc[e]) { mt -= tc[e]; ++e; }
  int m0 = mt * BM;
  int cnt_e = (e == NE) ? T_TOK : (int)cnt[e];

  const unsigned short* Bmat = (e == NE) ? WS : WE + (size_t)e * KDIM * NDIM;
  const float* bias = (e == NE) ? biasS : biasE + (size_t)e * NDIM;

  int tid = threadIdx.x, wave = tid >> 6, lane = tid & 63;
  int wm = wave >> 1, wn = wave & 1;
  int frow = lane & 15, fks = lane >> 4;

  int srow = wave * 8 + (lane >> 3);
  int sslot = lane & 7;
  const unsigned short* aptr[2][2];
  const unsigned short* bptr[2][2];
#pragma unroll
  for (int h = 0; h < 2; ++h)
#pragma unroll
    for (int j = 0; j < 2; ++j) {
      int rr = h * 128 + j * 64 + srow;
      int colsw = (sslot ^ (rr & 7)) << 3;
      int ar = m0 + rr;
      if (ar > cnt_e - 1) ar = cnt_e - 1;
      int gar;
      if (e == NE) gar = MODE1 ? ar : (2 * T_TOK + ar);
      else { int v = perm[(size_t)e * T_TOK + ar]; gar = MODE1 ? (v >> 1) : v; }
      aptr[h][j] = A + (size_t)gar * KDIM + colsw;
      bptr[h][j] = Bmat + (size_t)(n0 + rr) * KDIM + colsw;
    }

  auto stA = [&](int t, int h) {
    int dbe = (t & 1) * 16384;
    int k0 = t * BK;
    gload_lds16(aptr[h][0] + k0, &lds[dbe + h * 8192 + wave * 512]);
    gload_lds16(aptr[h][1] + k0, &lds[dbe + h * 8192 + wave * 512 + 4096]);
  };
  auto stB = [&](int t, int h) {
    int dbe = (t & 1) * 16384;
    int k0 = t * BK;
    gload_lds16(bptr[h][0] + k0, &lds[32768 + dbe + h * 8192 + wave * 512]);
    gload_lds16(bptr[h][1] + k0, &lds[32768 + dbe + h * 8192 + wave * 512 + 4096]);
  };

  auto rdA = [&](int dbe, int ks, int m) -> bf16x8 {
    int rr = wm * 64 + m * 16 + frow;
    int slot = (ks * 4 + fks) ^ (rr & 7);
    return *(const bf16x8*)&lds[dbe + rr * 64 + slot * 8];
  };
  auto rdB = [&](int dbe, int ks, int bh, int jj) -> bf16x8 {
    int rr = bh * 128 + jj * 32 + wn * 16 + frow;
    int slot = (ks * 4 + fks) ^ (rr & 7);
    return *(const bf16x8*)&lds[32768 + dbe + rr * 64 + slot * 8];
  };

  f32x4 acc[4][8];
#pragma unroll
  for (int m = 0; m < 4; ++m)
#pragma unroll
    for (int nn = 0; nn < 8; ++nn) acc[m][nn] = (f32x4){0.f, 0.f, 0.f, 0.f};

  stA(0, 0); stA(0, 1);
  stB(0, 0); stB(0, 1);
  stA(1, 0); stA(1, 1);
  WAITV(4);
  BARR();

  for (int t = 0; t < NKT; ++t) {
    const int dbe = (t & 1) * 16384;
    bf16x8 a0[4], a1[4], b0[4], b1[4];

#pragma unroll
    for (int m = 0; m < 4; ++m) a0[m] = rdA(dbe, 0, m);
#pragma unroll
    for (int m = 0; m < 4; ++m) a1[m] = rdA(dbe, 1, m);
#pragma unroll
    for (int jj = 0; jj < 4; ++jj) b0[jj] = rdB(dbe, 0, 0, jj);
#pragma unroll
    for (int jj = 0; jj < 4; ++jj) b1[jj] = rdB(dbe, 1, 0, jj);
    if (t + 1 < NKT) { stB(t + 1, 0); stB(t + 1, 1); }
    BARR();
    __builtin_amdgcn_s_setprio(1);
#pragma unroll
    for (int m = 0; m < 4; ++m)
#pragma unroll
      for (int jj = 0; jj < 4; ++jj)
        acc[m][jj] = __builtin_amdgcn_mfma_f32_16x16x32_bf16(a0[m], b0[jj], acc[m][jj], 0, 0, 0);
#pragma unroll
    for (int m = 0; m < 4; ++m)
#pragma unroll
      for (int jj = 0; jj < 4; ++jj)
        acc[m][jj] = __builtin_amdgcn_mfma_f32_16x16x32_bf16(a1[m], b1[jj], acc[m][jj], 0, 0, 0);
    __builtin_amdgcn_s_setprio(0);
    BARR();

#pragma unroll
    for (int jj = 0; jj < 4; ++jj) b0[jj] = rdB(dbe, 0, 1, jj);
#pragma unroll
    for (int jj = 0; jj < 4; ++jj) b1[jj] = rdB(dbe, 1, 1, jj);
    if (t + 2 < NKT) { stA(t + 2, 0); stA(t + 2, 1); }
    BARR();
    __builtin_amdgcn_s_setprio(1);
#pragma unroll
    for (int m = 0; m < 4; ++m)
#pragma unroll
      for (int jj = 0; jj < 4; ++jj)
        acc[m][4 + jj] = __builtin_amdgcn_mfma_f32_16x16x32_bf16(a0[m], b0[jj], acc[m][4 + jj], 0, 0, 0);
#pragma unroll
    for (int m = 0; m < 4; ++m)
#pragma unroll
      for (int jj = 0; jj < 4; ++jj)
        acc[m][4 + jj] = __builtin_amdgcn_mfma_f32_16x16x32_bf16(a1[m], b1[jj], acc[m][4 + jj], 0, 0, 0);
    __builtin_amdgcn_s_setprio(0);
    if (t + 2 < NKT) { WAITV(4); }
    else if (t + 1 < NKT) { WAITV(0); }
    BARR();
  }

#pragma unroll
  for (int m = 0; m < 4; ++m) {
#pragma unroll
    for (int qq = 0; qq < 4; ++qq) {
      int rt = wm * 64 + m * 16 + (lane >> 4) * 4 + qq;
      if (m0 + rt >= cnt_e) continue;
      int rr;
      if (e == NE) rr = 2 * T_TOK + m0 + rt;
      else rr = perm[(size_t)e * T_TOK + m0 + rt];
#pragma unroll
      for (int nn = 0; nn < 8; ++nn) {
        int col = n0 + (nn >> 2) * 128 + (nn & 3) * 32 + wn * 16 + (lane & 15);
        float val = acc[m][nn][qq] + bias[col];
        if (RELU) val = fmaxf(val, 0.f);
        if (MODE1 || OBF16)
          ((unsigned short*)outp)[(size_t)rr * NDIM + col] = f2bf(val);
        else
          ((float*)outp)[(size_t)rr * NDIM + col] = val;
      }
    }
  }
}

// ---------------------------------------------------------------- gemm1: GEMM | transpose W2 | em
__global__ __launch_bounds__(512, 2) void gemm1_kernel(
    const unsigned short* __restrict__ xb, const unsigned short* __restrict__ W1t,
    const unsigned short* __restrict__ sW1t, const float* __restrict__ b1,
    const float* __restrict__ sb1, const int* __restrict__ perm, const unsigned* __restrict__ cnt,
    unsigned short* __restrict__ Hbuf,
    const float* __restrict__ W2, const float* __restrict__ sW2,
    unsigned short* __restrict__ W2t, unsigned short* __restrict__ sW2t,
    const float* __restrict__ scores, const unsigned* __restrict__ usage,
    float* __restrict__ pbuf, float* __restrict__ loss_out) {
  __shared__ char smem[131072];
  int flat = blockIdx.x;
  if (flat < G1_GEMM) {
    gemm_body<D_DIM, H_DIM, true, true, false>((unsigned short*)smem, flat, xb, W1t, sW1t, b1,
                                               sb1, perm, cnt, (void*)Hbuf);
    return;
  }
  int l = flat - G1_GEMM;
  if (l < NTR128) {
    int m = l >> 7, rem = l & 127;
    int c0 = (rem & 7) * 128, r0 = (rem >> 3) * 128;
    const float* src = (m < NE) ? W2 + (size_t)m * H_DIM * D_DIM : sW2;
    unsigned short* dst = (m < NE) ? W2t + (size_t)m * H_DIM * D_DIM : sW2t;
    transpose_tile128(src, dst, H_DIM, D_DIM, r0, c0, threadIdx.x, (float*)smem);
    return;
  }
  em_block512(scores, usage, pbuf, loss_out, threadIdx.x, smem);
}

// ---------------------------------------------------------------- gemm2 (pure, bf16 out)
template <int KDIM, int NDIM, bool RELU, bool MODE1, bool OBF16>
__global__ __launch_bounds__(512, 2) void gemm_kernel(
    const unsigned short* __restrict__ A, const unsigned short* __restrict__ WE,
    const unsigned short* __restrict__ WS, const float* __restrict__ biasE,
    const float* __restrict__ biasS, const int* __restrict__ perm,
    const unsigned* __restrict__ cnt, void* __restrict__ outp) {
  __shared__ char smem[131072];
  gemm_body<KDIM, NDIM, RELU, MODE1, OBF16>((unsigned short*)smem, blockIdx.x, A, WE, WS, biasE,
                                            biasS, perm, cnt, outp);
}

// ---------------------------------------------------------------- combine (bf16 ebuf)
__global__ void combine_kernel(const unsigned short* __restrict__ ebuf,
                               const float* __restrict__ scores,
                               const float* __restrict__ p, const int* __restrict__ idx,
                               float* __restrict__ out) {
  int gid = blockIdx.x * blockDim.x + threadIdx.x;
  int t = gid >> 8;
  int d4 = gid & 255;
  int e0 = idx[t * 2], e1 = idx[t * 2 + 1];
  float w0 = scores[(size_t)t * NE + e0] * p[e0];
  float w1 = scores[(size_t)t * NE + e1] * p[e1];
  const ushort4* r0 = (const ushort4*)(ebuf + (size_t)(t * 2) * D_DIM);
  const ushort4* r1 = (const ushort4*)(ebuf + (size_t)(t * 2 + 1) * D_DIM);
  const ushort4* rs = (const ushort4*)(ebuf + (size_t)(2 * T_TOK + t) * D_DIM);
  ushort4 a = r0[d4], b = r1[d4], c = rs[d4];
  float4 o;
  o.x = w0 * bf2f(a.x) + w1 * bf2f(b.x) + 0.1f * bf2f(c.x);
  o.y = w0 * bf2f(a.y) + w1 * bf2f(b.y) + 0.1f * bf2f(c.y);
  o.z = w0 * bf2f(a.z) + w1 * bf2f(b.z) + 0.1f * bf2f(c.z);
  o.w = w0 * bf2f(a.w) + w1 * bf2f(b.w) + 0.1f * bf2f(c.w);
  ((float4*)out)[gid] = o;
}

// ---------------------------------------------------------------- launch
extern "C" void kernel_launch(void* const* d_in, const int* in_sizes, int n_in,
                              void* d_out, int out_size, void* d_ws, size_t ws_size,
                              hipStream_t stream) {
  const float* x     = (const float*)d_in[0];
  const float* gW    = (const float*)d_in[1];
  const float* gb    = (const float*)d_in[2];
  const float* gtemp = (const float*)d_in[3];
  const float* W1    = (const float*)d_in[4];
  const float* b1    = (const float*)d_in[5];
  const float* W2    = (const float*)d_in[6];
  const float* b2    = (const float*)d_in[7];
  const float* sW1   = (const float*)d_in[8];
  const float* sb1   = (const float*)d_in[9];
  const float* sW2   = (const float*)d_in[10];
  const float* sb2   = (const float*)d_in[11];
  float* out = (float*)d_out;

  char* ws = (char*)d_ws;
  size_t off = 0;
  auto take = [&](size_t b) { char* ptr = ws + off; off += (b + 255) & ~(size_t)255; return ptr; };
  unsigned short* xb   = (unsigned short*)take((size_t)T_TOK * D_DIM * 2);
  unsigned short* W1t  = (unsigned short*)take((size_t)NE * H_DIM * D_DIM * 2);
  unsigned short* sW1t = (unsigned short*)take((size_t)H_DIM * D_DIM * 2);
  unsigned short* W2t  = (unsigned short*)take((size_t)NE * D_DIM * H_DIM * 2);
  unsigned short* sW2t = (unsigned short*)take((size_t)D_DIM * H_DIM * 2);
  unsigned short* Hbuf = (unsigned short*)take((size_t)3 * T_TOK * H_DIM * 2);
  unsigned short* ebuf = (unsigned short*)take((size_t)3 * T_TOK * D_DIM * 2);
  float* scores        = (float*)take((size_t)T_TOK * NE * 4);
  int* idx             = (int*)take((size_t)T_TOK * 2 * 4);
  int* perm            = (int*)take((size_t)NE * T_TOK * 4);
  unsigned* cnt        = (unsigned*)take(256);
  unsigned* usage      = (unsigned*)take(256);
  float* pbuf          = (float*)take(256);
  (void)n_in; (void)in_sizes; (void)out_size; (void)ws_size;

  hipMemsetAsync(cnt, 0, 512, stream);  // cnt + usage (adjacent 256B blocks)
  prep2_kernel<<<512 + NTR128, 512, 0, stream>>>(x, gW, gb, gtemp, W1, sW1, W1t, sW1t, xb,
                                                 scores, idx, usage, cnt, perm);
  gemm1_kernel<<<G1_GEMM + NTR128 + 1, 512, 0, stream>>>(
      xb, W1t, sW1t, b1, sb1, perm, cnt, Hbuf, W2, sW2, W2t, sW2t, scores, usage, pbuf,
      out + (size_t)T_TOK * D_DIM);
  gemm_kernel<H_DIM, D_DIM, false, false, true><<<G2_GEMM, 512, 0, stream>>>(
      Hbuf, W2t, sW2t, b2, sb2, perm, cnt, (void*)ebuf);
  combine_kernel<<<(T_TOK * D_DIM / 4) / 256, 256, 0, stream>>>(ebuf, scores, pbuf, idx, out);
}